// Round 4
// baseline (943.449 us; speedup 1.0000x reference)
//
#include <hip/hip_runtime.h>

#define NN 8192
#define CHUNKS 128
#define CHUNK_ROWS (NN / CHUNKS)       // 64 rows per chunk
#define COLTILES 8                     // 8 tiles x 1024 cols
#define NPROD CHUNKS                   // 128 producer blocks (1 per chunk)
#define NCONS (CHUNKS * COLTILES)      // 1024 consumer blocks
#define MAGIC 0x5A5A5A5Au              // != 0xAAAAAAAA poison

// ws layout (floats): w[NN] | diag[NN] | partial[CHUNKS*NN] | flags[CHUNKS]

// Producer-consumer pipelined kernel.
// Blocks [0, NPROD): compute row sums for chunk c -> w[], diag[], set flag[c].
// Blocks [NPROD, NPROD+NCONS): spin on flag[c], then weighted partial column
// sums for (chunk c, col tile t). All 1152 blocks are co-resident
// (1152 * 4 waves = 4608 <= 5 blocks/CU * 256 CUs guaranteed by launch
// bounds), so the spin cannot deadlock regardless of dispatch order.
__global__ void __launch_bounds__(256, 5)
fused_pipe(const float* __restrict__ ts,
           const float* __restrict__ state,
           float* __restrict__ w,
           float* __restrict__ diag,
           float* __restrict__ partial,
           unsigned int* __restrict__ flags)
{
    const int tid  = threadIdx.x;
    const int lane = tid & 63;
    const int wid  = tid >> 6;

    if (blockIdx.x < NPROD) {
        // ---- producer: row sums of squares for 64 rows ----
        const int c    = blockIdx.x;
        const int row0 = c * CHUNK_ROWS;
        for (int r = wid; r < CHUNK_ROWS; r += 4) {       // 16 rows per wave
            const int row = row0 + r;
            const float4* rp = reinterpret_cast<const float4*>(ts + (size_t)row * NN);
            float sum = 0.f;
            #pragma unroll 8
            for (int k = lane; k < NN / 4; k += 64) {     // 32 iters
                float4 v = rp[k];
                sum += v.x * v.x + v.y * v.y + v.z * v.z + v.w * v.w;
            }
            #pragma unroll
            for (int off = 32; off; off >>= 1) sum += __shfl_down(sum, off);
            if (lane == 0) {
                float d = ts[(size_t)row * NN + row];
                d *= d;
                const float norm = fminf(d / (sum - d), 1.0f);
                __hip_atomic_store(&w[row], norm * state[3 * row + 2],
                                   __ATOMIC_RELAXED, __HIP_MEMORY_SCOPE_AGENT);
                diag[row] = d;        // consumed only past kernel boundary (K3)
            }
        }
        __threadfence();              // device-scope: w stores visible
        __syncthreads();
        if (tid == 0)
            __hip_atomic_store(&flags[c], MAGIC,
                               __ATOMIC_RELEASE, __HIP_MEMORY_SCOPE_AGENT);
    } else {
        // ---- consumer: weighted partial column sums for (chunk c, tile t) ----
        const int b = blockIdx.x - NPROD;
        const int c = b >> 3;                 // chunk
        const int t = b & 7;                  // column tile
        __shared__ float wsm[CHUNK_ROWS];

        if (tid == 0) {
            while (__hip_atomic_load(&flags[c], __ATOMIC_ACQUIRE,
                                     __HIP_MEMORY_SCOPE_AGENT) != MAGIC)
                __builtin_amdgcn_s_sleep(16);
        }
        __syncthreads();
        if (tid < CHUNK_ROWS)
            wsm[tid] = __hip_atomic_load(&w[c * CHUNK_ROWS + tid],
                                         __ATOMIC_RELAXED, __HIP_MEMORY_SCOPE_AGENT);
        __syncthreads();

        const int col  = t * 1024 + tid * 4;
        const int row0 = c * CHUNK_ROWS;
        const float* base = ts + (size_t)row0 * NN + col;
        float4 acc = {0.f, 0.f, 0.f, 0.f};
        #pragma unroll 8
        for (int r = 0; r < CHUNK_ROWS; ++r) {
            const float wi = wsm[r];
            float4 v = *reinterpret_cast<const float4*>(base + (size_t)r * NN);
            acc.x += wi * v.x * v.x;
            acc.y += wi * v.y * v.y;
            acc.z += wi * v.z * v.z;
            acc.w += wi * v.w * v.w;
        }
        *reinterpret_cast<float4*>(partial + (size_t)c * NN + col) = acc;
    }
}

// ---- K3: reduce partials + O(N) elementwise ----
__global__ void __launch_bounds__(256)
finalize(const float* __restrict__ state,
         const float* __restrict__ betas,
         const float* __restrict__ deltas,
         const float* __restrict__ cs,
         const float* __restrict__ ps,
         const float* __restrict__ w,
         const float* __restrict__ diag,
         const float* __restrict__ partial,
         float* __restrict__ out) {
    const int j = blockIdx.x * 256 + threadIdx.x;
    float coup = 0.f;
    #pragma unroll 8
    for (int c = 0; c < CHUNKS; ++c) coup += partial[(size_t)c * NN + j];
    const float dj = diag[j];
    coup -= w[j] * dj;                                  // remove i==j term

    const float U = state[3 * j + 0];
    const float I = state[3 * j + 1];
    const float V = state[3 * j + 2];
    const float b2 = betas[j] * betas[j];
    const float d2 = deltas[j] * deltas[j];
    const float p2 = ps[j] * ps[j];
    const float c2 = cs[j] * cs[j];
    const float bUV = b2 * U * V;

    out[3 * j + 0] = -bUV;
    out[3 * j + 1] = bUV - d2 * I;
    out[3 * j + 2] = p2 * I - c2 * V - dj + coup;
}

extern "C" void kernel_launch(void* const* d_in, const int* in_sizes, int n_in,
                              void* d_out, int out_size, void* d_ws, size_t ws_size,
                              hipStream_t stream) {
    // inputs: 0:t 1:state 2:betas 3:deltas 4:cs 5:ps 6:ts
    const float* state  = (const float*)d_in[1];
    const float* betas  = (const float*)d_in[2];
    const float* deltas = (const float*)d_in[3];
    const float* cs     = (const float*)d_in[4];
    const float* ps     = (const float*)d_in[5];
    const float* ts     = (const float*)d_in[6];
    float* out = (float*)d_out;

    float* w          = (float*)d_ws;
    float* diag       = w + NN;
    float* partial    = diag + NN;
    unsigned int* flags = (unsigned int*)(partial + (size_t)CHUNKS * NN);

    fused_pipe<<<NPROD + NCONS, 256, 0, stream>>>(ts, state, w, diag, partial, flags);

    finalize<<<NN / 256, 256, 0, stream>>>(state, betas, deltas, cs, ps,
                                           w, diag, partial, out);
}

// Round 5
// 410.123 us; speedup vs baseline: 2.3004x; 2.3004x over previous
//
#include <hip/hip_runtime.h>

#define NN 8192
#define RPB 8                  // rows per block
#define NBLK (NN / RPB)        // 1024 blocks
#define SUB 4                  // rows per sub-chunk = one per wave

// ws layout (floats): wv[NN] | diag[NN] | partial[NBLK*NN] | partial2[32*NN]

// Main kernel: block b owns rows [8b, 8b+8). For each 4-row sub-chunk:
//   pass A: wave w streams full row (8b + s*4 + w), sum of squares via
//           shuffle, computes w_r = min(d/(rs-d),1)*V_r locally (no cross-
//           block dependency), publishes w_r/diag_r for finalize.
//   pass B: wave w owns columns [2048w, 2048w+2048); re-reads the 4 rows
//           (just fetched -> L3 hit) accumulating w_r*ts^2 into LDS acc.
// One 32KB partial slice per block; no atomics, no spin, deterministic.
__global__ void __launch_bounds__(256, 4)
main_pass(const float* __restrict__ ts,
          const float* __restrict__ state,
          float* __restrict__ wv,
          float* __restrict__ diag,
          float* __restrict__ partial)
{
    __shared__ float acc[NN];          // 32 KB column accumulator
    __shared__ float wrow[SUB];

    const int tid  = threadIdx.x;
    const int lane = tid & 63;
    const int wid  = tid >> 6;

    #pragma unroll
    for (int i = tid; i < NN; i += 256) acc[i] = 0.f;

    const int row0 = blockIdx.x * RPB;

    for (int s = 0; s < RPB / SUB; ++s) {
        const int r = row0 + s * SUB + wid;            // this wave's row
        const float* rp = ts + (size_t)r * NN;
        // ---- pass A: row sum of squares (full width, 32 KB) ----
        float sum = 0.f;
        const float4* rp4 = (const float4*)rp;
        #pragma unroll 8
        for (int it = 0; it < 32; ++it) {
            float4 v = rp4[lane + it * 64];
            sum += v.x * v.x + v.y * v.y + v.z * v.z + v.w * v.w;
        }
        #pragma unroll
        for (int off = 32; off; off >>= 1) sum += __shfl_down(sum, off);
        if (lane == 0) {
            float d = rp[r]; d *= d;
            const float nrm = fminf(d / (sum - d), 1.0f);
            const float wr  = nrm * state[3 * r + 2];
            wrow[wid] = wr;
            wv[r]     = wr;
            diag[r]   = d;
        }
        __syncthreads();                               // wrow ready, acc safe
        // ---- pass B: weighted column accumulate, strip per wave ----
        const int colBase = wid * 2048;
        for (int rr = 0; rr < SUB; ++rr) {
            const float wr = wrow[rr];
            const float4* rq = (const float4*)(ts + (size_t)(row0 + s * SUB + rr) * NN + colBase);
            #pragma unroll 8
            for (int it = 0; it < 8; ++it) {
                const int idx = lane + it * 64;
                float4 v = rq[idx];
                float4* a = (float4*)&acc[colBase + idx * 4];
                float4 av = *a;
                av.x += wr * v.x * v.x;
                av.y += wr * v.y * v.y;
                av.z += wr * v.z * v.z;
                av.w += wr * v.w * v.w;
                *a = av;
            }
        }
        __syncthreads();                               // protect wrow reuse
    }
    // write the block's partial slice (32 KB, coalesced float4)
    float* pout = partial + (size_t)blockIdx.x * NN;
    #pragma unroll
    for (int i = tid; i < NN / 4; i += 256)
        ((float4*)pout)[i] = ((const float4*)acc)[i];
}

// Reduce 1024 slices -> 32 slices. grid(8, 32): x = col group (1024 cols),
// y = slice group (sums 32 slices). float4 coalesced.
__global__ void __launch_bounds__(256)
reduce1(const float* __restrict__ partial, float* __restrict__ partial2)
{
    const int col = blockIdx.x * 1024 + threadIdx.x * 4;
    const float* base = partial + (size_t)blockIdx.y * 32 * NN + col;
    float4 acc = {0.f, 0.f, 0.f, 0.f};
    #pragma unroll 8
    for (int k = 0; k < 32; ++k) {
        float4 v = *(const float4*)(base + (size_t)k * NN);
        acc.x += v.x; acc.y += v.y; acc.z += v.z; acc.w += v.w;
    }
    *(float4*)(partial2 + (size_t)blockIdx.y * NN + col) = acc;
}

// Reduce 32 slices + all O(N) elementwise math.
__global__ void __launch_bounds__(256)
finalize(const float* __restrict__ state,
         const float* __restrict__ betas,
         const float* __restrict__ deltas,
         const float* __restrict__ cs,
         const float* __restrict__ ps,
         const float* __restrict__ wv,
         const float* __restrict__ diag,
         const float* __restrict__ partial2,
         float* __restrict__ out)
{
    const int j = blockIdx.x * 256 + threadIdx.x;
    float coup = 0.f;
    #pragma unroll 8
    for (int k = 0; k < 32; ++k) coup += partial2[(size_t)k * NN + j];
    const float dj = diag[j];
    coup -= wv[j] * dj;                                // remove i==j term

    const float U = state[3 * j + 0];
    const float I = state[3 * j + 1];
    const float V = state[3 * j + 2];
    const float b2 = betas[j] * betas[j];
    const float d2 = deltas[j] * deltas[j];
    const float p2 = ps[j] * ps[j];
    const float c2 = cs[j] * cs[j];
    const float bUV = b2 * U * V;

    out[3 * j + 0] = -bUV;
    out[3 * j + 1] = bUV - d2 * I;
    out[3 * j + 2] = p2 * I - c2 * V - dj + coup;
}

extern "C" void kernel_launch(void* const* d_in, const int* in_sizes, int n_in,
                              void* d_out, int out_size, void* d_ws, size_t ws_size,
                              hipStream_t stream) {
    // inputs: 0:t 1:state 2:betas 3:deltas 4:cs 5:ps 6:ts
    const float* state  = (const float*)d_in[1];
    const float* betas  = (const float*)d_in[2];
    const float* deltas = (const float*)d_in[3];
    const float* cs     = (const float*)d_in[4];
    const float* ps     = (const float*)d_in[5];
    const float* ts     = (const float*)d_in[6];
    float* out = (float*)d_out;

    float* wv       = (float*)d_ws;
    float* diag     = wv + NN;
    float* partial  = diag + NN;
    float* partial2 = partial + (size_t)NBLK * NN;

    main_pass<<<NBLK, 256, 0, stream>>>(ts, state, wv, diag, partial);
    reduce1<<<dim3(8, 32), 256, 0, stream>>>(partial, partial2);
    finalize<<<NN / 256, 256, 0, stream>>>(state, betas, deltas, cs, ps,
                                           wv, diag, partial2, out);
}

// Round 6
// 377.364 us; speedup vs baseline: 2.5001x; 1.0868x over previous
//
#include <hip/hip_runtime.h>

#define NN 8192
#define RPB 8                  // rows per block
#define NBLK (NN / RPB)        // 1024 blocks
#define SLICE2 32              // second-stage slice count

// ws layout (floats): wv[NN] | diag[NN] | partial[NBLK*NN] | partial2[SLICE2*NN]

// Single-pass kernel: block b streams rows [8b, 8b+8) cooperatively, one row
// at a time. Each thread holds its 32 columns of the row in registers
// (8 float4), the block reduces the sum of squares (LDS), computes
// w_r = min(d/(rs-d),1)*V_r, broadcasts it, then FMAs the register-held
// values into per-thread column accumulators. The matrix is read from HBM
// EXACTLY ONCE. Next row is prefetched into registers before the reduce
// barriers so its latency overlaps the reduce.
__global__ void __launch_bounds__(256)
main_pass(const float* __restrict__ ts,
          const float* __restrict__ state,
          float* __restrict__ wv,
          float* __restrict__ diag,
          float* __restrict__ partial)
{
    __shared__ float red[4];
    __shared__ float wbc;

    const int tid  = threadIdx.x;
    const int lane = tid & 63;
    const int wid  = tid >> 6;
    const int row0 = blockIdx.x * RPB;

    float4 acc[8];
    #pragma unroll
    for (int k = 0; k < 8; ++k) acc[k] = make_float4(0.f, 0.f, 0.f, 0.f);

    float4 cur[8], nxt[8];
    {
        const float4* rp = (const float4*)(ts + (size_t)row0 * NN);
        #pragma unroll
        for (int k = 0; k < 8; ++k) cur[k] = rp[tid + k * 256];
    }

    #pragma unroll
    for (int r = 0; r < RPB; ++r) {
        const int row = row0 + r;
        if (r + 1 < RPB) {                 // prefetch next row (issued before barriers)
            const float4* np = (const float4*)(ts + (size_t)(row + 1) * NN);
            #pragma unroll
            for (int k = 0; k < 8; ++k) nxt[k] = np[tid + k * 256];
        }
        // partial sum of squares over this thread's 32 columns
        float s = 0.f;
        #pragma unroll
        for (int k = 0; k < 8; ++k) {
            float4 v = cur[k];
            s += v.x * v.x + v.y * v.y + v.z * v.z + v.w * v.w;
        }
        #pragma unroll
        for (int off = 32; off; off >>= 1) s += __shfl_down(s, off);
        if (lane == 0) red[wid] = s;
        __syncthreads();
        if (tid == 0) {
            const float total = red[0] + red[1] + red[2] + red[3];
            float d = ts[(size_t)row * NN + row];   // L1-hot: row just streamed
            d *= d;
            const float nrm = fminf(d / (total - d), 1.0f);
            const float wr  = nrm * state[3 * row + 2];
            wv[row]   = wr;
            diag[row] = d;
            wbc = wr;
        }
        __syncthreads();
        const float wr = wbc;
        #pragma unroll
        for (int k = 0; k < 8; ++k) {       // weighted accumulate from registers
            float4 v = cur[k];
            acc[k].x += wr * v.x * v.x;
            acc[k].y += wr * v.y * v.y;
            acc[k].z += wr * v.z * v.z;
            acc[k].w += wr * v.w * v.w;
        }
        if (r + 1 < RPB) {
            #pragma unroll
            for (int k = 0; k < 8; ++k) cur[k] = nxt[k];
        }
    }
    // write the block's partial slice (32 KB, coalesced float4)
    float4* po = (float4*)(partial + (size_t)blockIdx.x * NN);
    #pragma unroll
    for (int k = 0; k < 8; ++k) po[tid + k * 256] = acc[k];
}

// Reduce 1024 slices -> 32 slices. grid(8, 32): x = col group (1024 cols),
// y = slice group (sums 32 slices). float4 coalesced; source is L3-hot.
__global__ void __launch_bounds__(256)
reduce1(const float* __restrict__ partial, float* __restrict__ partial2)
{
    const int col = blockIdx.x * 1024 + threadIdx.x * 4;
    const float* base = partial + (size_t)blockIdx.y * 32 * NN + col;
    float4 acc = {0.f, 0.f, 0.f, 0.f};
    #pragma unroll 8
    for (int k = 0; k < 32; ++k) {
        float4 v = *(const float4*)(base + (size_t)k * NN);
        acc.x += v.x; acc.y += v.y; acc.z += v.z; acc.w += v.w;
    }
    *(float4*)(partial2 + (size_t)blockIdx.y * NN + col) = acc;
}

// Reduce 32 slices + all O(N) elementwise math.
__global__ void __launch_bounds__(256)
finalize(const float* __restrict__ state,
         const float* __restrict__ betas,
         const float* __restrict__ deltas,
         const float* __restrict__ cs,
         const float* __restrict__ ps,
         const float* __restrict__ wv,
         const float* __restrict__ diag,
         const float* __restrict__ partial2,
         float* __restrict__ out)
{
    const int j = blockIdx.x * 256 + threadIdx.x;
    float coup = 0.f;
    #pragma unroll 8
    for (int k = 0; k < SLICE2; ++k) coup += partial2[(size_t)k * NN + j];
    const float dj = diag[j];
    coup -= wv[j] * dj;                                // remove i==j term

    const float U = state[3 * j + 0];
    const float I = state[3 * j + 1];
    const float V = state[3 * j + 2];
    const float b2 = betas[j] * betas[j];
    const float d2 = deltas[j] * deltas[j];
    const float p2 = ps[j] * ps[j];
    const float c2 = cs[j] * cs[j];
    const float bUV = b2 * U * V;

    out[3 * j + 0] = -bUV;
    out[3 * j + 1] = bUV - d2 * I;
    out[3 * j + 2] = p2 * I - c2 * V - dj + coup;
}

extern "C" void kernel_launch(void* const* d_in, const int* in_sizes, int n_in,
                              void* d_out, int out_size, void* d_ws, size_t ws_size,
                              hipStream_t stream) {
    // inputs: 0:t 1:state 2:betas 3:deltas 4:cs 5:ps 6:ts
    const float* state  = (const float*)d_in[1];
    const float* betas  = (const float*)d_in[2];
    const float* deltas = (const float*)d_in[3];
    const float* cs     = (const float*)d_in[4];
    const float* ps     = (const float*)d_in[5];
    const float* ts     = (const float*)d_in[6];
    float* out = (float*)d_out;

    float* wv       = (float*)d_ws;
    float* diag     = wv + NN;
    float* partial  = diag + NN;
    float* partial2 = partial + (size_t)NBLK * NN;

    main_pass<<<NBLK, 256, 0, stream>>>(ts, state, wv, diag, partial);
    reduce1<<<dim3(8, SLICE2), 256, 0, stream>>>(partial, partial2);
    finalize<<<NN / 256, 256, 0, stream>>>(state, betas, deltas, cs, ps,
                                           wv, diag, partial2, out);
}